// Round 3
// baseline (4159.308 us; speedup 1.0000x reference)
//
#include <hip/hip_runtime.h>
#include <hip/hip_bf16.h>
#include <math.h>

#define N_NODES 50000
#define N_EDGES 800000
#define NH 4
#define DH 32
#define IN_DIM 256
#define OUTC 160
#define LS 570400     // int(0.713 * 800000) -> exactly 570400
#define RANK0 (LS - 1)

typedef unsigned long long u64;
#define SC_FX 1099511627776.0   // 2^40 fixed-point scale (ssum, gsums, oacc)

// ---- monotone float<->uint map (exact atomicMax for fp32 max; max precision is
// mathematically irrelevant to softmax result, fp32 is plenty) ----
__device__ __forceinline__ unsigned enc_f(float a){
  unsigned u = __float_as_uint(a);
  return (u & 0x80000000u) ? ~u : (u | 0x80000000u);
}
__device__ __forceinline__ float dec_f(unsigned k){
  return (k & 0x80000000u) ? __uint_as_float(k ^ 0x80000000u) : __uint_as_float(~k);
}

// ---- W1[k][j] = Wl[j][k]  (256 x 128, fp32) ----
__global__ void k_prepw1(const float* __restrict__ Wl, float* __restrict__ W1){
  int i = blockIdx.x * 256 + threadIdx.x;
  if (i >= IN_DIM * 128) return;
  int k = i >> 7, j = i & 127;
  W1[i] = Wl[j * IN_DIM + k];
}
// ---- W2[k][j] = [fc | fq] as f64 (256 x 256) ----
__global__ void k_prepw2(const float* __restrict__ fc, const float* __restrict__ fq,
                         double* __restrict__ W2){
  int i = blockIdx.x * 256 + threadIdx.x;
  if (i >= IN_DIM * 256) return;
  int k = i >> 8, j = i & 255;
  W2[i] = (double)((j < 128) ? fc[k * 128 + j] : fq[k * 128 + (j - 128)]);
}

// ---- fp32 GEMM: ft32[50000x128] = A[50000x256] * W1[256x128] ----
#define BM 128
#define BK 16
__global__ __launch_bounds__(256) void k_gemm32(const float* __restrict__ A,
                                                const float* __restrict__ W1,
                                                float* __restrict__ C){
  __shared__ float As[BK][BM + 4];
  __shared__ float Bs[BK][128 + 4];
  int tid = threadIdx.x;
  int m0 = blockIdx.x * BM;
  int ty = tid / 16, tx = tid % 16;
  float acc[8][8];
  #pragma unroll
  for (int i = 0; i < 8; i++)
    #pragma unroll
    for (int j = 0; j < 8; j++) acc[i][j] = 0.f;

  for (int k0 = 0; k0 < IN_DIM; k0 += BK){
    #pragma unroll
    for (int i = 0; i < 2; i++){
      int s = tid * 2 + i;
      int row = s >> 2, c4 = s & 3;
      int r = m0 + row;
      float4 v = make_float4(0.f, 0.f, 0.f, 0.f);
      if (r < N_NODES) v = *(const float4*)&A[(size_t)r * IN_DIM + k0 + c4 * 4];
      As[c4 * 4 + 0][row] = v.x; As[c4 * 4 + 1][row] = v.y;
      As[c4 * 4 + 2][row] = v.z; As[c4 * 4 + 3][row] = v.w;
    }
    #pragma unroll
    for (int i = 0; i < 2; i++){
      int s = tid * 2 + i;
      int kr = s >> 5, c4 = s & 31;
      if (c4 < 32){
        float4 v = *(const float4*)&W1[(size_t)(k0 + kr) * 128 + c4 * 4];
        *(float4*)&Bs[kr][c4 * 4] = v;
      }
    }
    __syncthreads();
    #pragma unroll
    for (int kk = 0; kk < BK; kk++){
      float4 a0 = *(const float4*)&As[kk][ty * 4];
      float4 a1 = *(const float4*)&As[kk][64 + ty * 4];
      float4 b0 = *(const float4*)&Bs[kk][tx * 4];
      float4 b1 = *(const float4*)&Bs[kk][64 + tx * 4];
      float av[8] = {a0.x, a0.y, a0.z, a0.w, a1.x, a1.y, a1.z, a1.w};
      float bv[8] = {b0.x, b0.y, b0.z, b0.w, b1.x, b1.y, b1.z, b1.w};
      #pragma unroll
      for (int i = 0; i < 8; i++)
        #pragma unroll
        for (int j = 0; j < 8; j++)
          acc[i][j] = fmaf(av[i], bv[j], acc[i][j]);
    }
    __syncthreads();
  }
  #pragma unroll
  for (int i = 0; i < 8; i++){
    int r = m0 + ((i < 4) ? (ty * 4 + i) : (64 + ty * 4 + (i - 4)));
    if (r >= N_NODES) continue;
    *(float4*)&C[(size_t)r * 128 + tx * 4]      = make_float4(acc[i][0], acc[i][1], acc[i][2], acc[i][3]);
    *(float4*)&C[(size_t)r * 128 + 64 + tx * 4] = make_float4(acc[i][4], acc[i][5], acc[i][6], acc[i][7]);
  }
}

// ---- fp64 GEMM: fcq64[50000x256] = A(f32->f64) * W2[256x256] ----
__global__ __launch_bounds__(256) void k_gemm64(const float* __restrict__ A,
                                                const double* __restrict__ W2,
                                                double* __restrict__ C){
  __shared__ double As[16][66];
  __shared__ double Bs[16][66];
  int tid = threadIdx.x;
  int m0 = blockIdx.x * 64;
  int n0 = blockIdx.y * 64;
  int ty = tid / 16, tx = tid % 16;
  double acc[4][4];
  #pragma unroll
  for (int i = 0; i < 4; i++)
    #pragma unroll
    for (int j = 0; j < 4; j++) acc[i][j] = 0.0;

  for (int k0 = 0; k0 < IN_DIM; k0 += 16){
    { // A tile: 64 rows x 16 k (f32 -> f64, transposed)
      int row = tid >> 2, c4 = tid & 3;
      int r = m0 + row;
      float4 v = make_float4(0.f, 0.f, 0.f, 0.f);
      if (r < N_NODES) v = *(const float4*)&A[(size_t)r * IN_DIM + k0 + c4 * 4];
      As[c4 * 4 + 0][row] = (double)v.x; As[c4 * 4 + 1][row] = (double)v.y;
      As[c4 * 4 + 2][row] = (double)v.z; As[c4 * 4 + 3][row] = (double)v.w;
    }
    { // B tile: 16 k x 64 n (f64)
      int kr = tid >> 4, c4 = tid & 15;
      const double* p = &W2[(size_t)(k0 + kr) * 256 + n0 + c4 * 4];
      double2 b0 = *(const double2*)p;
      double2 b1 = *(const double2*)(p + 2);
      Bs[kr][c4 * 4 + 0] = b0.x; Bs[kr][c4 * 4 + 1] = b0.y;
      Bs[kr][c4 * 4 + 2] = b1.x; Bs[kr][c4 * 4 + 3] = b1.y;
    }
    __syncthreads();
    #pragma unroll
    for (int kk = 0; kk < 16; kk++){
      double a[4], b[4];
      #pragma unroll
      for (int i = 0; i < 4; i++) a[i] = As[kk][ty * 4 + i];
      #pragma unroll
      for (int j = 0; j < 4; j++) b[j] = Bs[kk][tx * 4 + j];
      #pragma unroll
      for (int i = 0; i < 4; i++)
        #pragma unroll
        for (int j = 0; j < 4; j++)
          acc[i][j] = fma(a[i], b[j], acc[i][j]);
    }
    __syncthreads();
  }
  #pragma unroll
  for (int i = 0; i < 4; i++){
    int r = m0 + ty * 4 + i;
    if (r >= N_NODES) continue;
    double* p = &C[(size_t)r * 256 + n0 + tx * 4];
    *(double2*)p       = make_double2(acc[i][0], acc[i][1]);
    *(double2*)(p + 2) = make_double2(acc[i][2], acc[i][3]);
  }
}

// ---- head-mean of ft into out[:,128:160] ----
__global__ void k_mean(const float* __restrict__ ft, float* __restrict__ out){
  int i = blockIdx.x * 256 + threadIdx.x;
  if (i >= N_NODES * DH) return;
  int n = i / DH, dd = i % DH;
  const float* p = ft + (size_t)n * 128;
  out[(size_t)n * OUTC + 128 + dd] = 0.25f * (p[dd] + p[32 + dd] + p[64 + dd] + p[96 + dd]);
}

// ---- edge logits (f64) + fp32 segment-max ----
__global__ __launch_bounds__(256) void k_edge_a(const double* __restrict__ fcq,
    const int* __restrict__ src, const int* __restrict__ dst,
    double* __restrict__ abuf, unsigned* __restrict__ menc){
  int wid = blockIdx.x * 4 + (threadIdx.x >> 6);
  int t = threadIdx.x & 63;
  if (wid >= N_EDGES) return;
  int s = src[wid], d = dst[wid];
  const double* qp = fcq + (size_t)s * 256 + 128;  // ftq row
  const double* cp = fcq + (size_t)d * 256;        // ftc row
  double2 q = *(const double2*)&qp[t * 2];
  double2 c = *(const double2*)&cp[t * 2];
  double val = (q.x - c.x) * c.x + (q.y - c.y) * c.y;
  val += __shfl_xor(val, 1);
  val += __shfl_xor(val, 2);
  val += __shfl_xor(val, 4);
  val += __shfl_xor(val, 8);
  if ((t & 15) == 0){
    int hh = t >> 4;
    double a = (val > 0.0) ? val : expm1(val);     // ELU (f64)
    abuf[(size_t)wid * 4 + hh] = a;
    atomicMax(&menc[(size_t)d * 4 + hh], enc_f((float)a));
  }
}

// ---- ex = exp(a - m); ssum[dst] += ex (fixed-point u64) ----
__global__ void k_ex_sum(const int* __restrict__ dst, double* __restrict__ abuf,
                         const unsigned* __restrict__ menc, u64* __restrict__ ssum64){
  int i = blockIdx.x * 256 + threadIdx.x;
  if (i >= N_EDGES * 4) return;
  int e = i >> 2, hh = i & 3;
  int d = dst[e];
  double m = (double)dec_f(menc[(size_t)d * 4 + hh]);
  double ex = exp(abuf[i] - m);
  abuf[i] = ex;
  atomicAdd(&ssum64[(size_t)d * 4 + hh], (u64)llrint(ex * SC_FX));
}

// ---- attn = ex / s ----
__global__ void k_attn(const int* __restrict__ dst, double* __restrict__ abuf,
                       const u64* __restrict__ ssum64){
  int i = blockIdx.x * 256 + threadIdx.x;
  if (i >= N_EDGES * 4) return;
  int e = i >> 2, hh = i & 3;
  double s = (double)ssum64[(size_t)dst[e] * 4 + hh] * (1.0 / SC_FX);
  abuf[i] = abuf[i] / s;
}

// ---- radix-select over 64-bit keys (attn > 0 -> raw bits are ordered) ----
__global__ void k_hist(const double* __restrict__ attn, const u64* __restrict__ sel4,
                       unsigned* __restrict__ hist, u64 maskHi, int shift){
  __shared__ unsigned lh[1024];
  for (int j = threadIdx.x; j < 1024; j += 256) lh[j] = 0;
  __syncthreads();
  int i0 = blockIdx.x * 256 + threadIdx.x;
  int hh = i0 & 3;                   // stride multiple of 4 -> head fixed
  u64 sel = sel4[hh];
  const int total = N_EDGES * 4;
  for (int i = i0; i < total; i += gridDim.x * 256){
    u64 u = (u64)__double_as_longlong(attn[i]);
    if ((u & maskHi) == sel)
      atomicAdd(&lh[hh * 256 + (unsigned)((u >> shift) & 255u)], 1u);
  }
  __syncthreads();
  for (int j = threadIdx.x; j < 1024; j += 256)
    if (lh[j]) atomicAdd(&hist[j], lh[j]);
}

__global__ void k_pick(unsigned* __restrict__ hist, u64* __restrict__ sel4,
                       unsigned* __restrict__ krem, unsigned* __restrict__ cnt, int shift){
  __shared__ unsigned lh[1024];
  int t = threadIdx.x;
  for (int j = t; j < 1024; j += 256){ lh[j] = hist[j]; hist[j] = 0; }
  __syncthreads();
  if (t < 4){
    unsigned kr = krem[t];
    unsigned cum = 0, b = 0;
    for (; b < 256; b++){
      unsigned c = lh[t * 256 + b];
      if (kr < cum + c) break;
      cum += c;
    }
    sel4[t] |= ((u64)b) << shift;
    krem[t]  = kr - cum;
    cnt[t]  += cum;
  }
}

__global__ void k_init(unsigned* __restrict__ krem){
  if (threadIdx.x < 4) krem[threadIdx.x] = RANK0;
}

// ---- per-head sums below/above threshold (fixed-point u64) ----
__global__ void k_sums(const double* __restrict__ attn, const u64* __restrict__ sel4,
                       u64* __restrict__ gsums){
  int t = threadIdx.x;
  int i0 = blockIdx.x * 256 + t;
  int hh = i0 & 3;
  double thd = __longlong_as_double((long long)sel4[hh]);
  double al = 0.0, ag = 0.0;
  const int total = N_EDGES * 4;
  for (int i = i0; i < total; i += gridDim.x * 256){
    double v = attn[i];
    if (v < thd) al += v; else ag += v;
  }
  long long ql = llrint(al * SC_FX);
  long long qg = llrint(ag * SC_FX);
  if (ql) atomicAdd(&gsums[hh],     (u64)ql);
  if (qg) atomicAdd(&gsums[4 + hh], (u64)qg);
}

// ---- thd + ratio per head (f64) ----
__global__ void k_ratio(const u64* __restrict__ sel4, const unsigned* __restrict__ cnt,
                        const u64* __restrict__ gsums, double* __restrict__ trd){
  int t = threadIdx.x;
  if (t < 4){
    double thd = __longlong_as_double((long long)sel4[t]);
    double sless = (double)gsums[t]     * (1.0 / SC_FX);
    double sge   = (double)gsums[4 + t] * (1.0 / SC_FX);
    double topk  = sless + (double)(LS - (int)cnt[t]) * thd;
    trd[t] = thd;
    trd[4 + t] = (sge + topk) / sge;
  }
}

// ---- weighted scatter into fixed-point u64 accumulator ----
__global__ __launch_bounds__(256) void k_scatter(const float* __restrict__ ft,
    const int* __restrict__ src, const int* __restrict__ dst,
    const double* __restrict__ attn, const double* __restrict__ trd,
    u64* __restrict__ oacc){
  int wid = blockIdx.x * 4 + (threadIdx.x >> 6);
  int t = threadIdx.x & 63;
  if (wid >= N_EDGES) return;
  int hh = t >> 4;
  double w = attn[(size_t)wid * 4 + hh];
  double thd = trd[hh], ratio = trd[4 + hh];
  double a3 = (w < thd) ? 0.0 : w * ratio;
  if (__ballot(a3 != 0.0) == 0ull) return;   // whole edge dropped (~71%)
  if (a3 != 0.0){
    int s = src[wid], d = dst[wid];
    float2 f = *(const float2*)&ft[(size_t)s * 128 + t * 2];
    u64* p = &oacc[(size_t)d * 128 + t * 2];
    atomicAdd(p,     (u64)llrint(a3 * (double)f.x * SC_FX));
    atomicAdd(p + 1, (u64)llrint(a3 * (double)f.y * SC_FX));
  }
}

// ---- fixed-point accumulator -> out[:, :128] ----
__global__ void k_out_cvt(const u64* __restrict__ oacc, float* __restrict__ out){
  int i = blockIdx.x * 256 + threadIdx.x;
  if (i >= N_NODES * 128) return;
  int n = i >> 7, c = i & 127;
  out[(size_t)n * OUTC + c] = (float)((double)(long long)oacc[i] * (1.0 / SC_FX));
}

extern "C" void kernel_launch(void* const* d_in, const int* in_sizes, int n_in,
                              void* d_out, int out_size, void* d_ws, size_t ws_size,
                              hipStream_t stream){
  const float* h  = (const float*)d_in[0];
  const float* Wl = (const float*)d_in[1];
  const float* fc = (const float*)d_in[2];
  const float* fq = (const float*)d_in[3];
  const int* src  = (const int*)d_in[4];
  const int* dst  = (const int*)d_in[5];
  float* out = (float*)d_out;

  char* ws = (char*)d_ws;
  float*  W1    = (float*)(ws);                      // 131,072 B
  double* W2    = (double*)(ws + 131072);            // 524,288 B
  float*  ft32  = (float*)(ws + 655360);             // 25,600,000 B
  double* fcq64 = (double*)(ws + 26255360);          // 102,400,000 B
  u64*    oacc  = (u64*)(ws + 26255360);             // 51,200,000 B (aliases fcq64, used after edge_a)
  double* abuf  = (double*)(ws + 128655360);         // 25,600,000 B
  unsigned* menc = (unsigned*)(ws + 154255360);      // 800,000 B
  u64*    ssum64 = (u64*)(ws + 155055360);           // 1,600,000 B
  unsigned* hist = (unsigned*)(ws + 156655360);      // 4,096 B
  u64*    sel4  = (u64*)(ws + 156659456);            // 32 B
  unsigned* krem = (unsigned*)(ws + 156659488);      // 16 B
  unsigned* cnt  = (unsigned*)(ws + 156659504);      // 16 B
  u64*    gsums = (u64*)(ws + 156659520);            // 64 B
  double* trd   = (double*)(ws + 156659584);         // 64 B

  // zero per-call accumulators (hist..gsums contiguous: 4096+32+16+16+64)
  hipMemsetAsync(menc, 0, 800000, stream);
  hipMemsetAsync(ssum64, 0, 1600000, stream);
  hipMemsetAsync(hist, 0, 4224, stream);
  k_init<<<1, 64, 0, stream>>>(krem);

  k_prepw1<<<(IN_DIM * 128 + 255) / 256, 256, 0, stream>>>(Wl, W1);
  k_prepw2<<<(IN_DIM * 256 + 255) / 256, 256, 0, stream>>>(fc, fq, W2);
  k_gemm32<<<(N_NODES + BM - 1) / BM, 256, 0, stream>>>(h, W1, ft32);
  dim3 g64((N_NODES + 63) / 64, 4);
  k_gemm64<<<g64, 256, 0, stream>>>(h, W2, fcq64);
  k_mean<<<(N_NODES * DH + 255) / 256, 256, 0, stream>>>(ft32, out);

  k_edge_a<<<N_EDGES / 4, 256, 0, stream>>>(fcq64, src, dst, abuf, menc);

  // fcq64 dead from here; reuse region as oacc
  hipMemsetAsync(oacc, 0, 51200000, stream);

  k_ex_sum<<<(N_EDGES * 4 + 255) / 256, 256, 0, stream>>>(dst, abuf, menc, ssum64);
  k_attn<<<(N_EDGES * 4 + 255) / 256, 256, 0, stream>>>(dst, abuf, ssum64);

  for (int p = 0; p < 8; p++){
    u64 maskHi = (p == 0) ? 0ull : (~0ull) << (64 - 8 * p);
    int shift = 56 - 8 * p;
    k_hist<<<2048, 256, 0, stream>>>(abuf, sel4, hist, maskHi, shift);
    k_pick<<<1, 256, 0, stream>>>(hist, sel4, krem, cnt, shift);
  }
  k_sums<<<2048, 256, 0, stream>>>(abuf, sel4, gsums);
  k_ratio<<<1, 64, 0, stream>>>(sel4, cnt, gsums, trd);

  k_scatter<<<N_EDGES / 4, 256, 0, stream>>>(ft32, src, dst, abuf, trd, oacc);
  k_out_cvt<<<(N_NODES * 128 + 255) / 256, 256, 0, stream>>>(oacc, out);
}

// Round 4
// 1172.891 us; speedup vs baseline: 3.5462x; 3.5462x over previous
//
#include <hip/hip_runtime.h>
#include <hip/hip_bf16.h>
#include <math.h>

#define N_NODES 50000
#define N_EDGES 800000
#define NH 4
#define DH 32
#define IN_DIM 256
#define OUTC 160
#define LS 570400     // int(0.713 * 800000) -> exactly 570400
#define RANK0 (LS - 1)

typedef unsigned long long u64;
#define SC_FX 1099511627776.0   // 2^40 fixed-point scale (ssum, gsums, oacc)

// ---- monotone float<->uint map (exact atomicMax for fp32 max) ----
__device__ __forceinline__ unsigned enc_f(float a){
  unsigned u = __float_as_uint(a);
  return (u & 0x80000000u) ? ~u : (u | 0x80000000u);
}
__device__ __forceinline__ float dec_f(unsigned k){
  return (k & 0x80000000u) ? __uint_as_float(k ^ 0x80000000u) : __uint_as_float(~k);
}

// ---- W1[k][j] = Wl[j][k]  (256 x 128, fp32) ----
__global__ void k_prepw1(const float* __restrict__ Wl, float* __restrict__ W1){
  int i = blockIdx.x * 256 + threadIdx.x;
  if (i >= IN_DIM * 128) return;
  int k = i >> 7, j = i & 127;
  W1[i] = Wl[j * IN_DIM + k];
}
// ---- W2[k][j] = [fc | fq] as f64 (256 x 256) ----
__global__ void k_prepw2(const float* __restrict__ fc, const float* __restrict__ fq,
                         double* __restrict__ W2){
  int i = blockIdx.x * 256 + threadIdx.x;
  if (i >= IN_DIM * 256) return;
  int k = i >> 8, j = i & 255;
  W2[i] = (double)((j < 128) ? fc[k * 128 + j] : fq[k * 128 + (j - 128)]);
}

// ---- fp32 GEMM: ft32[50000x128] = A[50000x256] * W1[256x128] ----
#define BM 128
#define BK 16
__global__ __launch_bounds__(256) void k_gemm32(const float* __restrict__ A,
                                                const float* __restrict__ W1,
                                                float* __restrict__ C){
  __shared__ float As[BK][BM + 4];
  __shared__ float Bs[BK][128 + 4];
  int tid = threadIdx.x;
  int m0 = blockIdx.x * BM;
  int ty = tid / 16, tx = tid % 16;
  float acc[8][8];
  #pragma unroll
  for (int i = 0; i < 8; i++)
    #pragma unroll
    for (int j = 0; j < 8; j++) acc[i][j] = 0.f;

  for (int k0 = 0; k0 < IN_DIM; k0 += BK){
    #pragma unroll
    for (int i = 0; i < 2; i++){
      int s = tid * 2 + i;
      int row = s >> 2, c4 = s & 3;
      int r = m0 + row;
      float4 v = make_float4(0.f, 0.f, 0.f, 0.f);
      if (r < N_NODES) v = *(const float4*)&A[(size_t)r * IN_DIM + k0 + c4 * 4];
      As[c4 * 4 + 0][row] = v.x; As[c4 * 4 + 1][row] = v.y;
      As[c4 * 4 + 2][row] = v.z; As[c4 * 4 + 3][row] = v.w;
    }
    #pragma unroll
    for (int i = 0; i < 2; i++){
      int s = tid * 2 + i;
      int kr = s >> 5, c4 = s & 31;
      if (c4 < 32){
        float4 v = *(const float4*)&W1[(size_t)(k0 + kr) * 128 + c4 * 4];
        *(float4*)&Bs[kr][c4 * 4] = v;
      }
    }
    __syncthreads();
    #pragma unroll
    for (int kk = 0; kk < BK; kk++){
      float4 a0 = *(const float4*)&As[kk][ty * 4];
      float4 a1 = *(const float4*)&As[kk][64 + ty * 4];
      float4 b0 = *(const float4*)&Bs[kk][tx * 4];
      float4 b1 = *(const float4*)&Bs[kk][64 + tx * 4];
      float av[8] = {a0.x, a0.y, a0.z, a0.w, a1.x, a1.y, a1.z, a1.w};
      float bv[8] = {b0.x, b0.y, b0.z, b0.w, b1.x, b1.y, b1.z, b1.w};
      #pragma unroll
      for (int i = 0; i < 8; i++)
        #pragma unroll
        for (int j = 0; j < 8; j++)
          acc[i][j] = fmaf(av[i], bv[j], acc[i][j]);
    }
    __syncthreads();
  }
  #pragma unroll
  for (int i = 0; i < 8; i++){
    int r = m0 + ((i < 4) ? (ty * 4 + i) : (64 + ty * 4 + (i - 4)));
    if (r >= N_NODES) continue;
    *(float4*)&C[(size_t)r * 128 + tx * 4]      = make_float4(acc[i][0], acc[i][1], acc[i][2], acc[i][3]);
    *(float4*)&C[(size_t)r * 128 + 64 + tx * 4] = make_float4(acc[i][4], acc[i][5], acc[i][6], acc[i][7]);
  }
}

// ---- fp64 GEMM: fcq64[50000x256] = A(f32->f64) * W2[256x256] ----
__global__ __launch_bounds__(256) void k_gemm64(const float* __restrict__ A,
                                                const double* __restrict__ W2,
                                                double* __restrict__ C){
  __shared__ double As[16][66];
  __shared__ double Bs[16][66];
  int tid = threadIdx.x;
  int m0 = blockIdx.x * 64;
  int n0 = blockIdx.y * 64;
  int ty = tid / 16, tx = tid % 16;
  double acc[4][4];
  #pragma unroll
  for (int i = 0; i < 4; i++)
    #pragma unroll
    for (int j = 0; j < 4; j++) acc[i][j] = 0.0;

  for (int k0 = 0; k0 < IN_DIM; k0 += 16){
    {
      int row = tid >> 2, c4 = tid & 3;
      int r = m0 + row;
      float4 v = make_float4(0.f, 0.f, 0.f, 0.f);
      if (r < N_NODES) v = *(const float4*)&A[(size_t)r * IN_DIM + k0 + c4 * 4];
      As[c4 * 4 + 0][row] = (double)v.x; As[c4 * 4 + 1][row] = (double)v.y;
      As[c4 * 4 + 2][row] = (double)v.z; As[c4 * 4 + 3][row] = (double)v.w;
    }
    {
      int kr = tid >> 4, c4 = tid & 15;
      const double* p = &W2[(size_t)(k0 + kr) * 256 + n0 + c4 * 4];
      double2 b0 = *(const double2*)p;
      double2 b1 = *(const double2*)(p + 2);
      Bs[kr][c4 * 4 + 0] = b0.x; Bs[kr][c4 * 4 + 1] = b0.y;
      Bs[kr][c4 * 4 + 2] = b1.x; Bs[kr][c4 * 4 + 3] = b1.y;
    }
    __syncthreads();
    #pragma unroll
    for (int kk = 0; kk < 16; kk++){
      double a[4], b[4];
      #pragma unroll
      for (int i = 0; i < 4; i++) a[i] = As[kk][ty * 4 + i];
      #pragma unroll
      for (int j = 0; j < 4; j++) b[j] = Bs[kk][tx * 4 + j];
      #pragma unroll
      for (int i = 0; i < 4; i++)
        #pragma unroll
        for (int j = 0; j < 4; j++)
          acc[i][j] = fma(a[i], b[j], acc[i][j]);
    }
    __syncthreads();
  }
  #pragma unroll
  for (int i = 0; i < 4; i++){
    int r = m0 + ty * 4 + i;
    if (r >= N_NODES) continue;
    double* p = &C[(size_t)r * 256 + n0 + tx * 4];
    *(double2*)p       = make_double2(acc[i][0], acc[i][1]);
    *(double2*)(p + 2) = make_double2(acc[i][2], acc[i][3]);
  }
}

// ---- head-mean of ft into out[:,128:160] ----
__global__ void k_mean(const float* __restrict__ ft, float* __restrict__ out){
  int i = blockIdx.x * 256 + threadIdx.x;
  if (i >= N_NODES * DH) return;
  int n = i / DH, dd = i % DH;
  const float* p = ft + (size_t)n * 128;
  out[(size_t)n * OUTC + 128 + dd] = 0.25f * (p[dd] + p[32 + dd] + p[64 + dd] + p[96 + dd]);
}

// ---- edge logits (f64) + fp32 segment-max ----
__global__ __launch_bounds__(256) void k_edge_a(const double* __restrict__ fcq,
    const int* __restrict__ src, const int* __restrict__ dst,
    double* __restrict__ abuf, unsigned* __restrict__ menc){
  int wid = blockIdx.x * 4 + (threadIdx.x >> 6);
  int t = threadIdx.x & 63;
  if (wid >= N_EDGES) return;
  int s = src[wid], d = dst[wid];
  const double* qp = fcq + (size_t)s * 256 + 128;  // ftq row
  const double* cp = fcq + (size_t)d * 256;        // ftc row
  double2 q = *(const double2*)&qp[t * 2];
  double2 c = *(const double2*)&cp[t * 2];
  double val = (q.x - c.x) * c.x + (q.y - c.y) * c.y;
  val += __shfl_xor(val, 1);
  val += __shfl_xor(val, 2);
  val += __shfl_xor(val, 4);
  val += __shfl_xor(val, 8);
  if ((t & 15) == 0){
    int hh = t >> 4;
    double a = (val > 0.0) ? val : expm1(val);     // ELU (f64)
    abuf[(size_t)wid * 4 + hh] = a;
    atomicMax(&menc[(size_t)d * 4 + hh], enc_f((float)a));
  }
}

// ---- ex = exp(a - m); ssum[dst] += ex (fixed-point u64) ----
__global__ void k_ex_sum(const int* __restrict__ dst, double* __restrict__ abuf,
                         const unsigned* __restrict__ menc, u64* __restrict__ ssum64){
  int i = blockIdx.x * 256 + threadIdx.x;
  if (i >= N_EDGES * 4) return;
  int e = i >> 2, hh = i & 3;
  int d = dst[e];
  double m = (double)dec_f(menc[(size_t)d * 4 + hh]);
  double ex = exp(abuf[i] - m);
  abuf[i] = ex;
  atomicAdd(&ssum64[(size_t)d * 4 + hh], (u64)llrint(ex * SC_FX));
}

// ---- attn = ex / s ----
__global__ void k_attn(const int* __restrict__ dst, double* __restrict__ abuf,
                       const u64* __restrict__ ssum64){
  int i = blockIdx.x * 256 + threadIdx.x;
  if (i >= N_EDGES * 4) return;
  int e = i >> 2, hh = i & 3;
  double s = (double)ssum64[(size_t)dst[e] * 4 + hh] * (1.0 / SC_FX);
  abuf[i] = abuf[i] / s;
}

// ---- radix-select over 64-bit keys (attn > 0 -> raw bits are ordered) ----
__global__ void k_hist(const double* __restrict__ attn, const u64* __restrict__ sel4,
                       unsigned* __restrict__ hist, u64 maskHi, int shift){
  __shared__ unsigned lh[1024];
  for (int j = threadIdx.x; j < 1024; j += 256) lh[j] = 0;
  __syncthreads();
  int i0 = blockIdx.x * 256 + threadIdx.x;
  int hh = i0 & 3;                   // stride multiple of 4 -> head fixed
  u64 sel = sel4[hh];
  const int total = N_EDGES * 4;
  for (int i = i0; i < total; i += gridDim.x * 256){
    u64 u = (u64)__double_as_longlong(attn[i]);
    if ((u & maskHi) == sel)
      atomicAdd(&lh[hh * 256 + (unsigned)((u >> shift) & 255u)], 1u);
  }
  __syncthreads();
  for (int j = threadIdx.x; j < 1024; j += 256)
    if (lh[j]) atomicAdd(&hist[j], lh[j]);
}

__global__ void k_pick(unsigned* __restrict__ hist, u64* __restrict__ sel4,
                       unsigned* __restrict__ krem, unsigned* __restrict__ cnt, int shift){
  __shared__ unsigned lh[1024];
  int t = threadIdx.x;
  for (int j = t; j < 1024; j += 256){ lh[j] = hist[j]; hist[j] = 0; }
  __syncthreads();
  if (t < 4){
    unsigned kr = krem[t];
    unsigned cum = 0, b = 0;
    for (; b < 256; b++){
      unsigned c = lh[t * 256 + b];
      if (kr < cum + c) break;
      cum += c;
    }
    sel4[t] |= ((u64)b) << shift;
    krem[t]  = kr - cum;
    cnt[t]  += cum;
  }
}

__global__ void k_init(unsigned* __restrict__ krem){
  if (threadIdx.x < 4) krem[threadIdx.x] = RANK0;
}

// ---- per-head sums below/above threshold, hierarchical (shfl+LDS) reduction ----
__global__ __launch_bounds__(256) void k_sums(const double* __restrict__ attn,
                                              const u64* __restrict__ sel4,
                                              u64* __restrict__ gsums){
  int t = threadIdx.x;
  int i0 = blockIdx.x * 256 + t;
  int hh = t & 3;                       // grid stride is multiple of 4 -> head fixed
  double thd = __longlong_as_double((long long)sel4[hh]);
  double al = 0.0, ag = 0.0;
  const int total = N_EDGES * 4;
  for (int i = i0; i < total; i += gridDim.x * 256){
    double v = attn[i];
    if (v < thd) al += v; else ag += v;
  }
  long long ql = llrint(al * SC_FX);
  long long qg = llrint(ag * SC_FX);
  // reduce over lanes with the same (t & 3): xor distances 4,8,16,32
  #pragma unroll
  for (int m = 4; m < 64; m <<= 1){
    ql += __shfl_xor(ql, m);
    qg += __shfl_xor(qg, m);
  }
  __shared__ long long sl[16], sg[16];  // 4 waves x 4 heads
  int wv = t >> 6;
  if ((t & 63) < 4){ sl[wv * 4 + hh] = ql; sg[wv * 4 + hh] = qg; }
  __syncthreads();
  if (t < 4){
    long long a = sl[t] + sl[4 + t] + sl[8 + t] + sl[12 + t];
    long long b = sg[t] + sg[4 + t] + sg[8 + t] + sg[12 + t];
    if (a) atomicAdd(&gsums[t],     (u64)a);
    if (b) atomicAdd(&gsums[4 + t], (u64)b);
  }
}

// ---- thd + ratio per head (f64) ----
__global__ void k_ratio(const u64* __restrict__ sel4, const unsigned* __restrict__ cnt,
                        const u64* __restrict__ gsums, double* __restrict__ trd){
  int t = threadIdx.x;
  if (t < 4){
    double thd = __longlong_as_double((long long)sel4[t]);
    double sless = (double)gsums[t]     * (1.0 / SC_FX);
    double sge   = (double)gsums[4 + t] * (1.0 / SC_FX);
    double topk  = sless + (double)(LS - (int)cnt[t]) * thd;
    trd[t] = thd;
    trd[4 + t] = (sge + topk) / sge;
  }
}

// ---- weighted scatter into fixed-point u64 accumulator ----
__global__ __launch_bounds__(256) void k_scatter(const float* __restrict__ ft,
    const int* __restrict__ src, const int* __restrict__ dst,
    const double* __restrict__ attn, const double* __restrict__ trd,
    u64* __restrict__ oacc){
  int wid = blockIdx.x * 4 + (threadIdx.x >> 6);
  int t = threadIdx.x & 63;
  if (wid >= N_EDGES) return;
  int hh = t >> 4;
  double w = attn[(size_t)wid * 4 + hh];
  double thd = trd[hh], ratio = trd[4 + hh];
  double a3 = (w < thd) ? 0.0 : w * ratio;
  if (__ballot(a3 != 0.0) == 0ull) return;   // whole edge dropped (~71%)
  if (a3 != 0.0){
    int s = src[wid], d = dst[wid];
    float2 f = *(const float2*)&ft[(size_t)s * 128 + t * 2];
    u64* p = &oacc[(size_t)d * 128 + t * 2];
    atomicAdd(p,     (u64)llrint(a3 * (double)f.x * SC_FX));
    atomicAdd(p + 1, (u64)llrint(a3 * (double)f.y * SC_FX));
  }
}

// ---- fixed-point accumulator -> out[:, :128] ----
__global__ void k_out_cvt(const u64* __restrict__ oacc, float* __restrict__ out){
  int i = blockIdx.x * 256 + threadIdx.x;
  if (i >= N_NODES * 128) return;
  int n = i >> 7, c = i & 127;
  out[(size_t)n * OUTC + c] = (float)((double)(long long)oacc[i] * (1.0 / SC_FX));
}

extern "C" void kernel_launch(void* const* d_in, const int* in_sizes, int n_in,
                              void* d_out, int out_size, void* d_ws, size_t ws_size,
                              hipStream_t stream){
  const float* h  = (const float*)d_in[0];
  const float* Wl = (const float*)d_in[1];
  const float* fc = (const float*)d_in[2];
  const float* fq = (const float*)d_in[3];
  const int* src  = (const int*)d_in[4];
  const int* dst  = (const int*)d_in[5];
  float* out = (float*)d_out;

  char* ws = (char*)d_ws;
  float*  W1    = (float*)(ws);                      // 131,072 B
  double* W2    = (double*)(ws + 131072);            // 524,288 B
  float*  ft32  = (float*)(ws + 655360);             // 25,600,000 B
  double* fcq64 = (double*)(ws + 26255360);          // 102,400,000 B
  u64*    oacc  = (u64*)(ws + 26255360);             // 51,200,000 B (aliases fcq64, dead after edge_a)
  double* abuf  = (double*)(ws + 128655360);         // 25,600,000 B
  unsigned* menc = (unsigned*)(ws + 154255360);      // 800,000 B
  u64*    ssum64 = (u64*)(ws + 155055360);           // 1,600,000 B
  unsigned* hist = (unsigned*)(ws + 156655360);      // 4,096 B
  u64*    sel4  = (u64*)(ws + 156659456);            // 32 B
  unsigned* krem = (unsigned*)(ws + 156659488);      // 16 B
  unsigned* cnt  = (unsigned*)(ws + 156659504);      // 16 B
  u64*    gsums = (u64*)(ws + 156659520);            // 64 B
  double* trd   = (double*)(ws + 156659584);         // 64 B

  hipMemsetAsync(menc, 0, 800000, stream);
  hipMemsetAsync(ssum64, 0, 1600000, stream);
  hipMemsetAsync(hist, 0, 4224, stream);   // hist + sel4 + krem + cnt + gsums
  k_init<<<1, 64, 0, stream>>>(krem);

  k_prepw1<<<(IN_DIM * 128 + 255) / 256, 256, 0, stream>>>(Wl, W1);
  k_prepw2<<<(IN_DIM * 256 + 255) / 256, 256, 0, stream>>>(fc, fq, W2);
  k_gemm32<<<(N_NODES + BM - 1) / BM, 256, 0, stream>>>(h, W1, ft32);
  dim3 g64((N_NODES + 63) / 64, 4);
  k_gemm64<<<g64, 256, 0, stream>>>(h, W2, fcq64);
  k_mean<<<(N_NODES * DH + 255) / 256, 256, 0, stream>>>(ft32, out);

  k_edge_a<<<N_EDGES / 4, 256, 0, stream>>>(fcq64, src, dst, abuf, menc);

  // fcq64 dead from here; reuse region as oacc
  hipMemsetAsync(oacc, 0, 51200000, stream);

  k_ex_sum<<<(N_EDGES * 4 + 255) / 256, 256, 0, stream>>>(dst, abuf, menc, ssum64);
  k_attn<<<(N_EDGES * 4 + 255) / 256, 256, 0, stream>>>(dst, abuf, ssum64);

  for (int p = 0; p < 8; p++){
    u64 maskHi = (p == 0) ? 0ull : (~0ull) << (64 - 8 * p);
    int shift = 56 - 8 * p;
    k_hist<<<2048, 256, 0, stream>>>(abuf, sel4, hist, maskHi, shift);
    k_pick<<<1, 256, 0, stream>>>(hist, sel4, krem, cnt, shift);
  }
  k_sums<<<2048, 256, 0, stream>>>(abuf, sel4, gsums);
  k_ratio<<<1, 64, 0, stream>>>(sel4, cnt, gsums, trd);

  k_scatter<<<N_EDGES / 4, 256, 0, stream>>>(ft32, src, dst, abuf, trd, oacc);
  k_out_cvt<<<(N_NODES * 128 + 255) / 256, 256, 0, stream>>>(oacc, out);
}

// Round 5
// 1107.954 us; speedup vs baseline: 3.7540x; 1.0586x over previous
//
#include <hip/hip_runtime.h>
#include <hip/hip_bf16.h>
#include <math.h>

#define N_NODES 50000
#define N_EDGES 800000
#define NH 4
#define DH 32
#define IN_DIM 256
#define OUTC 160
#define LS 570400     // int(0.713 * 800000) -> exactly 570400
#define RANK0 (LS - 1)

typedef unsigned long long u64;
#define SC_FX 1099511627776.0   // 2^40 fixed-point scale

// ---- monotone float<->uint map (exact atomicMax for fp32 max) ----
__device__ __forceinline__ unsigned enc_f(float a){
  unsigned u = __float_as_uint(a);
  return (u & 0x80000000u) ? ~u : (u | 0x80000000u);
}
__device__ __forceinline__ float dec_f(unsigned k){
  return (k & 0x80000000u) ? __uint_as_float(k ^ 0x80000000u) : __uint_as_float(~k);
}

// ---- W1[k][j] = Wl[j][k]  (256 x 128, fp32) ----
__global__ void k_prepw1(const float* __restrict__ Wl, float* __restrict__ W1){
  int i = blockIdx.x * 256 + threadIdx.x;
  if (i >= IN_DIM * 128) return;
  int k = i >> 7, j = i & 127;
  W1[i] = Wl[j * IN_DIM + k];
}
// ---- W2[k][j] = [fc | fq] as f64 (256 x 256) ----
__global__ void k_prepw2(const float* __restrict__ fc, const float* __restrict__ fq,
                         double* __restrict__ W2){
  int i = blockIdx.x * 256 + threadIdx.x;
  if (i >= IN_DIM * 256) return;
  int k = i >> 8, j = i & 255;
  W2[i] = (double)((j < 128) ? fc[k * 128 + j] : fq[k * 128 + (j - 128)]);
}

// ---- fp32 GEMM: ft32[50000x128] = A[50000x256] * W1[256x128] ----
#define BM 128
#define BK 16
__global__ __launch_bounds__(256) void k_gemm32(const float* __restrict__ A,
                                                const float* __restrict__ W1,
                                                float* __restrict__ C){
  __shared__ float As[BK][BM + 4];
  __shared__ float Bs[BK][128 + 4];
  int tid = threadIdx.x;
  int m0 = blockIdx.x * BM;
  int ty = tid / 16, tx = tid % 16;
  float acc[8][8];
  #pragma unroll
  for (int i = 0; i < 8; i++)
    #pragma unroll
    for (int j = 0; j < 8; j++) acc[i][j] = 0.f;

  for (int k0 = 0; k0 < IN_DIM; k0 += BK){
    #pragma unroll
    for (int i = 0; i < 2; i++){
      int s = tid * 2 + i;
      int row = s >> 2, c4 = s & 3;
      int r = m0 + row;
      float4 v = make_float4(0.f, 0.f, 0.f, 0.f);
      if (r < N_NODES) v = *(const float4*)&A[(size_t)r * IN_DIM + k0 + c4 * 4];
      As[c4 * 4 + 0][row] = v.x; As[c4 * 4 + 1][row] = v.y;
      As[c4 * 4 + 2][row] = v.z; As[c4 * 4 + 3][row] = v.w;
    }
    #pragma unroll
    for (int i = 0; i < 2; i++){
      int s = tid * 2 + i;
      int kr = s >> 5, c4 = s & 31;
      if (c4 < 32){
        float4 v = *(const float4*)&W1[(size_t)(k0 + kr) * 128 + c4 * 4];
        *(float4*)&Bs[kr][c4 * 4] = v;
      }
    }
    __syncthreads();
    #pragma unroll
    for (int kk = 0; kk < BK; kk++){
      float4 a0 = *(const float4*)&As[kk][ty * 4];
      float4 a1 = *(const float4*)&As[kk][64 + ty * 4];
      float4 b0 = *(const float4*)&Bs[kk][tx * 4];
      float4 b1 = *(const float4*)&Bs[kk][64 + tx * 4];
      float av[8] = {a0.x, a0.y, a0.z, a0.w, a1.x, a1.y, a1.z, a1.w};
      float bv[8] = {b0.x, b0.y, b0.z, b0.w, b1.x, b1.y, b1.z, b1.w};
      #pragma unroll
      for (int i = 0; i < 8; i++)
        #pragma unroll
        for (int j = 0; j < 8; j++)
          acc[i][j] = fmaf(av[i], bv[j], acc[i][j]);
    }
    __syncthreads();
  }
  #pragma unroll
  for (int i = 0; i < 8; i++){
    int r = m0 + ((i < 4) ? (ty * 4 + i) : (64 + ty * 4 + (i - 4)));
    if (r >= N_NODES) continue;
    *(float4*)&C[(size_t)r * 128 + tx * 4]      = make_float4(acc[i][0], acc[i][1], acc[i][2], acc[i][3]);
    *(float4*)&C[(size_t)r * 128 + 64 + tx * 4] = make_float4(acc[i][4], acc[i][5], acc[i][6], acc[i][7]);
  }
}

// ---- fp64 GEMM: fcq64[50000x256] = A(f32->f64) * W2[256x256] ----
__global__ __launch_bounds__(256) void k_gemm64(const float* __restrict__ A,
                                                const double* __restrict__ W2,
                                                double* __restrict__ C){
  __shared__ double As[16][66];
  __shared__ double Bs[16][66];
  int tid = threadIdx.x;
  int m0 = blockIdx.x * 64;
  int n0 = blockIdx.y * 64;
  int ty = tid / 16, tx = tid % 16;
  double acc[4][4];
  #pragma unroll
  for (int i = 0; i < 4; i++)
    #pragma unroll
    for (int j = 0; j < 4; j++) acc[i][j] = 0.0;

  for (int k0 = 0; k0 < IN_DIM; k0 += 16){
    {
      int row = tid >> 2, c4 = tid & 3;
      int r = m0 + row;
      float4 v = make_float4(0.f, 0.f, 0.f, 0.f);
      if (r < N_NODES) v = *(const float4*)&A[(size_t)r * IN_DIM + k0 + c4 * 4];
      As[c4 * 4 + 0][row] = (double)v.x; As[c4 * 4 + 1][row] = (double)v.y;
      As[c4 * 4 + 2][row] = (double)v.z; As[c4 * 4 + 3][row] = (double)v.w;
    }
    {
      int kr = tid >> 4, c4 = tid & 15;
      const double* p = &W2[(size_t)(k0 + kr) * 256 + n0 + c4 * 4];
      double2 b0 = *(const double2*)p;
      double2 b1 = *(const double2*)(p + 2);
      Bs[kr][c4 * 4 + 0] = b0.x; Bs[kr][c4 * 4 + 1] = b0.y;
      Bs[kr][c4 * 4 + 2] = b1.x; Bs[kr][c4 * 4 + 3] = b1.y;
    }
    __syncthreads();
    #pragma unroll
    for (int kk = 0; kk < 16; kk++){
      double a[4], b[4];
      #pragma unroll
      for (int i = 0; i < 4; i++) a[i] = As[kk][ty * 4 + i];
      #pragma unroll
      for (int j = 0; j < 4; j++) b[j] = Bs[kk][tx * 4 + j];
      #pragma unroll
      for (int i = 0; i < 4; i++)
        #pragma unroll
        for (int j = 0; j < 4; j++)
          acc[i][j] = fma(a[i], b[j], acc[i][j]);
    }
    __syncthreads();
  }
  #pragma unroll
  for (int i = 0; i < 4; i++){
    int r = m0 + ty * 4 + i;
    if (r >= N_NODES) continue;
    double* p = &C[(size_t)r * 256 + n0 + tx * 4];
    *(double2*)p       = make_double2(acc[i][0], acc[i][1]);
    *(double2*)(p + 2) = make_double2(acc[i][2], acc[i][3]);
  }
}

// ---- head-mean of ft into out[:,128:160] ----
__global__ void k_mean(const float* __restrict__ ft, float* __restrict__ out){
  int i = blockIdx.x * 256 + threadIdx.x;
  if (i >= N_NODES * DH) return;
  int n = i / DH, dd = i % DH;
  const float* p = ft + (size_t)n * 128;
  out[(size_t)n * OUTC + 128 + dd] = 0.25f * (p[dd] + p[32 + dd] + p[64 + dd] + p[96 + dd]);
}

// ---- edge logits (f64) + fp32 segment-max ----
__global__ __launch_bounds__(256) void k_edge_a(const double* __restrict__ fcq,
    const int* __restrict__ src, const int* __restrict__ dst,
    double* __restrict__ abuf, unsigned* __restrict__ menc){
  int wid = blockIdx.x * 4 + (threadIdx.x >> 6);
  int t = threadIdx.x & 63;
  if (wid >= N_EDGES) return;
  int s = src[wid], d = dst[wid];
  const double* qp = fcq + (size_t)s * 256 + 128;  // ftq row
  const double* cp = fcq + (size_t)d * 256;        // ftc row
  double2 q = *(const double2*)&qp[t * 2];
  double2 c = *(const double2*)&cp[t * 2];
  double val = (q.x - c.x) * c.x + (q.y - c.y) * c.y;
  val += __shfl_xor(val, 1);
  val += __shfl_xor(val, 2);
  val += __shfl_xor(val, 4);
  val += __shfl_xor(val, 8);
  if ((t & 15) == 0){
    int hh = t >> 4;
    double a = (val > 0.0) ? val : expm1(val);     // ELU (f64)
    abuf[(size_t)wid * 4 + hh] = a;
    atomicMax(&menc[(size_t)d * 4 + hh], enc_f((float)a));
  }
}

// ---- ex = exp(a - m); ssum[dst] += ex (fixed-point u64) ----
__global__ void k_ex_sum(const int* __restrict__ dst, double* __restrict__ abuf,
                         const unsigned* __restrict__ menc, u64* __restrict__ ssum64){
  int i = blockIdx.x * 256 + threadIdx.x;
  if (i >= N_EDGES * 4) return;
  int e = i >> 2, hh = i & 3;
  int d = dst[e];
  double m = (double)dec_f(menc[(size_t)d * 4 + hh]);
  double ex = exp(abuf[i] - m);
  abuf[i] = ex;
  atomicAdd(&ssum64[(size_t)d * 4 + hh], (u64)llrint(ex * SC_FX));
}

// ---- attn = ex / s ----
__global__ void k_attn(const int* __restrict__ dst, double* __restrict__ abuf,
                       const u64* __restrict__ ssum64){
  int i = blockIdx.x * 256 + threadIdx.x;
  if (i >= N_EDGES * 4) return;
  int e = i >> 2, hh = i & 3;
  double s = (double)ssum64[(size_t)dst[e] * 4 + hh] * (1.0 / SC_FX);
  abuf[i] = abuf[i] / s;
}

// ---- CSR build: degree, scan, cursor copy, fill ----
__global__ void k_deg(const int* __restrict__ dst, unsigned* __restrict__ deg){
  int e = blockIdx.x * 256 + threadIdx.x;
  if (e < N_EDGES) atomicAdd(&deg[dst[e]], 1u);
}

__global__ __launch_bounds__(1024) void k_scan(const unsigned* __restrict__ deg,
                                               unsigned* __restrict__ offsets){
  __shared__ unsigned ps[1024];
  int t = threadIdx.x;
  const int CH = (N_NODES + 1023) / 1024;   // 49
  int base = t * CH;
  unsigned s = 0;
  for (int i = 0; i < CH; i++){
    int n = base + i;
    if (n < N_NODES) s += deg[n];
  }
  ps[t] = s;
  __syncthreads();
  for (int off = 1; off < 1024; off <<= 1){
    unsigned v = (t >= off) ? ps[t - off] : 0;
    __syncthreads();
    ps[t] += v;
    __syncthreads();
  }
  unsigned ex = (t == 0) ? 0 : ps[t - 1];
  for (int i = 0; i < CH; i++){
    int n = base + i;
    if (n < N_NODES){ offsets[n] = ex; ex += deg[n]; }
  }
  if (t == 1023) offsets[N_NODES] = ps[1023];
}

__global__ void k_cpcur(const unsigned* __restrict__ offsets, unsigned* __restrict__ cur){
  int i = blockIdx.x * 256 + threadIdx.x;
  if (i < N_NODES) cur[i] = offsets[i];
}

__global__ void k_fill(const int* __restrict__ dst, unsigned* __restrict__ cur,
                       unsigned* __restrict__ eidx){
  int e = blockIdx.x * 256 + threadIdx.x;
  if (e < N_EDGES) eidx[atomicAdd(&cur[dst[e]], 1u)] = (unsigned)e;
}

// ---- radix-select over 64-bit keys (attn > 0 -> raw bits are ordered) ----
__global__ void k_hist(const double* __restrict__ attn, const u64* __restrict__ sel4,
                       unsigned* __restrict__ hist, u64 maskHi, int shift){
  __shared__ unsigned lh[1024];
  for (int j = threadIdx.x; j < 1024; j += 256) lh[j] = 0;
  __syncthreads();
  int i0 = blockIdx.x * 256 + threadIdx.x;
  int hh = i0 & 3;
  u64 sel = sel4[hh];
  const int total = N_EDGES * 4;
  for (int i = i0; i < total; i += gridDim.x * 256){
    u64 u = (u64)__double_as_longlong(attn[i]);
    if ((u & maskHi) == sel)
      atomicAdd(&lh[hh * 256 + (unsigned)((u >> shift) & 255u)], 1u);
  }
  __syncthreads();
  for (int j = threadIdx.x; j < 1024; j += 256)
    if (lh[j]) atomicAdd(&hist[j], lh[j]);
}

__global__ void k_pick(unsigned* __restrict__ hist, u64* __restrict__ sel4,
                       unsigned* __restrict__ krem, unsigned* __restrict__ cnt, int shift){
  __shared__ unsigned lh[1024];
  int t = threadIdx.x;
  for (int j = t; j < 1024; j += 256){ lh[j] = hist[j]; hist[j] = 0; }
  __syncthreads();
  if (t < 4){
    unsigned kr = krem[t];
    unsigned cum = 0, b = 0;
    for (; b < 256; b++){
      unsigned c = lh[t * 256 + b];
      if (kr < cum + c) break;
      cum += c;
    }
    sel4[t] |= ((u64)b) << shift;
    krem[t]  = kr - cum;
    cnt[t]  += cum;
  }
}

__global__ void k_init(unsigned* __restrict__ krem){
  if (threadIdx.x < 4) krem[threadIdx.x] = RANK0;
}

// ---- per-head sums below/above threshold, hierarchical reduction ----
__global__ __launch_bounds__(256) void k_sums(const double* __restrict__ attn,
                                              const u64* __restrict__ sel4,
                                              u64* __restrict__ gsums){
  int t = threadIdx.x;
  int i0 = blockIdx.x * 256 + t;
  int hh = t & 3;
  double thd = __longlong_as_double((long long)sel4[hh]);
  double al = 0.0, ag = 0.0;
  const int total = N_EDGES * 4;
  for (int i = i0; i < total; i += gridDim.x * 256){
    double v = attn[i];
    if (v < thd) al += v; else ag += v;
  }
  long long ql = llrint(al * SC_FX);
  long long qg = llrint(ag * SC_FX);
  #pragma unroll
  for (int m = 4; m < 64; m <<= 1){
    ql += __shfl_xor(ql, m);
    qg += __shfl_xor(qg, m);
  }
  __shared__ long long sl[16], sg[16];
  int wv = t >> 6;
  if ((t & 63) < 4){ sl[wv * 4 + hh] = ql; sg[wv * 4 + hh] = qg; }
  __syncthreads();
  if (t < 4){
    long long a = sl[t] + sl[4 + t] + sl[8 + t] + sl[12 + t];
    long long b = sg[t] + sg[4 + t] + sg[8 + t] + sg[12 + t];
    if (a) atomicAdd(&gsums[t],     (u64)a);
    if (b) atomicAdd(&gsums[4 + t], (u64)b);
  }
}

// ---- thd + ratio per head (f64) ----
__global__ void k_ratio(const u64* __restrict__ sel4, const unsigned* __restrict__ cnt,
                        const u64* __restrict__ gsums, double* __restrict__ trd){
  int t = threadIdx.x;
  if (t < 4){
    double thd = __longlong_as_double((long long)sel4[t]);
    double sless = (double)gsums[t]     * (1.0 / SC_FX);
    double sge   = (double)gsums[4 + t] * (1.0 / SC_FX);
    double topk  = sless + (double)(LS - (int)cnt[t]) * thd;
    trd[t] = thd;
    trd[4 + t] = (sge + topk) / sge;
  }
}

// ---- CSR gather-scatter: one wave per dst node, int64 fixed-point in registers ----
__global__ __launch_bounds__(256) void k_scatter2(const float* __restrict__ ft,
    const int* __restrict__ src, const unsigned* __restrict__ offsets,
    const unsigned* __restrict__ eidx, const double* __restrict__ attn,
    const double* __restrict__ trd, float* __restrict__ out){
  int d = blockIdx.x * 4 + (threadIdx.x >> 6);
  int t = threadIdx.x & 63;
  if (d >= N_NODES) return;
  int hh = t >> 4;
  double thd = trd[hh], ratio = trd[4 + hh];
  unsigned k0 = offsets[d], k1 = offsets[d + 1];
  long long acc0 = 0, acc1 = 0;
  for (unsigned k = k0; k < k1; k++){
    unsigned e = eidx[k];
    double w = attn[(size_t)e * 4 + hh];
    double a3 = (w < thd) ? 0.0 : w * ratio;
    if (__ballot(a3 != 0.0) == 0ull) continue;   // edge dropped for all heads
    if (a3 != 0.0){
      int s = src[e];
      float2 f = *(const float2*)&ft[(size_t)s * 128 + t * 2];
      acc0 += llrint(a3 * (double)f.x * SC_FX);
      acc1 += llrint(a3 * (double)f.y * SC_FX);
    }
  }
  float* p = &out[(size_t)d * OUTC + t * 2];
  p[0] = (float)((double)acc0 * (1.0 / SC_FX));
  p[1] = (float)((double)acc1 * (1.0 / SC_FX));
}

extern "C" void kernel_launch(void* const* d_in, const int* in_sizes, int n_in,
                              void* d_out, int out_size, void* d_ws, size_t ws_size,
                              hipStream_t stream){
  const float* h  = (const float*)d_in[0];
  const float* Wl = (const float*)d_in[1];
  const float* fc = (const float*)d_in[2];
  const float* fq = (const float*)d_in[3];
  const int* src  = (const int*)d_in[4];
  const int* dst  = (const int*)d_in[5];
  float* out = (float*)d_out;

  char* ws = (char*)d_ws;
  float*  W1    = (float*)(ws);                      // 131,072 B
  double* W2    = (double*)(ws + 131072);            // 524,288 B
  float*  ft32  = (float*)(ws + 655360);             // 25,600,000 B
  double* fcq64 = (double*)(ws + 26255360);          // 102,400,000 B (dead after k_edge_a)
  // CSR buffers alias fcq64 (used only after k_edge_a):
  unsigned* offsets = (unsigned*)(ws + 26255360);    // 200,004 B
  unsigned* cur     = (unsigned*)(ws + 26455368);    // 200,000 B (also deg)
  unsigned* eidx    = (unsigned*)(ws + 26655368);    // 3,200,000 B
  double* abuf  = (double*)(ws + 128655360);         // 25,600,000 B
  unsigned* menc = (unsigned*)(ws + 154255360);      // 800,000 B
  u64*    ssum64 = (u64*)(ws + 155055360);           // 1,600,000 B
  unsigned* hist = (unsigned*)(ws + 156655360);      // 4,096 B
  u64*    sel4  = (u64*)(ws + 156659456);            // 32 B
  unsigned* krem = (unsigned*)(ws + 156659488);      // 16 B
  unsigned* cnt  = (unsigned*)(ws + 156659504);      // 16 B
  u64*    gsums = (u64*)(ws + 156659520);            // 64 B
  double* trd   = (double*)(ws + 156659584);         // 64 B

  hipMemsetAsync(menc, 0, 800000, stream);
  hipMemsetAsync(ssum64, 0, 1600000, stream);
  hipMemsetAsync(hist, 0, 4224, stream);   // hist + sel4 + krem + cnt + gsums
  k_init<<<1, 64, 0, stream>>>(krem);

  k_prepw1<<<(IN_DIM * 128 + 255) / 256, 256, 0, stream>>>(Wl, W1);
  k_prepw2<<<(IN_DIM * 256 + 255) / 256, 256, 0, stream>>>(fc, fq, W2);
  k_gemm32<<<(N_NODES + BM - 1) / BM, 256, 0, stream>>>(h, W1, ft32);
  dim3 g64((N_NODES + 63) / 64, 4);
  k_gemm64<<<g64, 256, 0, stream>>>(h, W2, fcq64);
  k_mean<<<(N_NODES * DH + 255) / 256, 256, 0, stream>>>(ft32, out);

  k_edge_a<<<N_EDGES / 4, 256, 0, stream>>>(fcq64, src, dst, abuf, menc);

  // fcq64 dead from here; build CSR in its place
  hipMemsetAsync(cur, 0, 200000, stream);            // deg = 0
  k_deg<<<(N_EDGES + 255) / 256, 256, 0, stream>>>(dst, cur);
  k_scan<<<1, 1024, 0, stream>>>(cur, offsets);
  k_cpcur<<<(N_NODES + 255) / 256, 256, 0, stream>>>(offsets, cur);
  k_fill<<<(N_EDGES + 255) / 256, 256, 0, stream>>>(dst, cur, eidx);

  k_ex_sum<<<(N_EDGES * 4 + 255) / 256, 256, 0, stream>>>(dst, abuf, menc, ssum64);
  k_attn<<<(N_EDGES * 4 + 255) / 256, 256, 0, stream>>>(dst, abuf, ssum64);

  for (int p = 0; p < 8; p++){
    u64 maskHi = (p == 0) ? 0ull : (~0ull) << (64 - 8 * p);
    int shift = 56 - 8 * p;
    k_hist<<<2048, 256, 0, stream>>>(abuf, sel4, hist, maskHi, shift);
    k_pick<<<1, 256, 0, stream>>>(hist, sel4, krem, cnt, shift);
  }
  k_sums<<<2048, 256, 0, stream>>>(abuf, sel4, gsums);
  k_ratio<<<1, 64, 0, stream>>>(sel4, cnt, gsums, trd);

  k_scatter2<<<(N_NODES + 3) / 4, 256, 0, stream>>>(ft32, src, offsets, eidx, abuf, trd, out);
}